// Round 11
// baseline (112.711 us; speedup 1.0000x reference)
//
#include <hip/hip_runtime.h>
#include <hip/hip_bf16.h>

typedef __attribute__((ext_vector_type(8))) short bf16x8;
typedef __attribute__((ext_vector_type(4))) short s16x4;
typedef __attribute__((ext_vector_type(4))) float f32x4;

__device__ __forceinline__ short f2b(float f) {
    __hip_bfloat16 h = __float2bfloat16(f);   // RNE
    return __builtin_bit_cast(short, h);
}

#define KT 512      // K-tile in floats (2 KB/row f32, 1 KB/row bf16 in LDS)
#define NT 8        // 4096 / 512

// Instrumentation: pure-read ceiling probe. 2048 blocks x 256 threads, each
// block streams a contiguous 64 KB chunk of W (128 MiB total) lane-linearly,
// accumulates, writes 1 float/thread to a dead ws region. Deterministic and
// output-neutral. rocprof dur of THIS dispatch = the chip's pure-read rate
// for this buffer (the constant all 10 rounds of inference were missing).
__global__ void __launch_bounds__(256) wread_bench(const float4* __restrict__ Wv,
                                                   float* __restrict__ sink) {
    const int tid = threadIdx.x;
    const size_t base = (size_t)blockIdx.x * 4096;   // 4096 float4 = 64 KB
    float4 a = {0.f, 0.f, 0.f, 0.f};
    #pragma unroll
    for (int i = 0; i < 16; ++i) {
        float4 v = Wv[base + i * 256 + tid];
        a.x += v.x; a.y += v.y; a.z += v.z; a.w += v.w;
    }
    sink[blockIdx.x * 256 + tid] = a.x + a.y + a.z + a.w;
}

// Kernel 1: x f32 -> bf16, and y2 = 2*(x @ A^T) as bf16.
__global__ void prep_kernel(const float* __restrict__ x,
                            const float* __restrict__ A,
                            ushort* __restrict__ xb,     // [64][4096] bf16
                            ushort* __restrict__ yb) {   // [64][64] bf16
    const int tid = threadIdx.x, bid = blockIdx.x;

    const int gid = bid * 256 + tid;
    if (gid < 65536) {
        float4 v = ((const float4*)x)[gid];
        ushort4 s;
        s.x = (ushort)f2b(v.x); s.y = (ushort)f2b(v.y);
        s.z = (ushort)f2b(v.z); s.w = (ushort)f2b(v.w);
        ((ushort4*)xb)[gid] = s;
    }

    const int wave = tid >> 6, lane = tid & 63;
    const int idx = bid * 4 + wave;          // 0..4095
    const int t = idx >> 6, r = idx & 63;
    const float4* xr = (const float4*)(x + (size_t)t * 4096);
    const float4* ar = (const float4*)(A + (size_t)r * 4096);
    float s = 0.f;
    #pragma unroll
    for (int i = 0; i < 16; ++i) {
        float4 a = xr[i * 64 + lane];
        float4 b = ar[i * 64 + lane];
        s += a.x * b.x + a.y * b.y + a.z * b.z + a.w * b.w;
    }
    #pragma unroll
    for (int off = 32; off; off >>= 1) s += __shfl_xor(s, off, 64);
    if (lane == 0) yb[idx] = (ushort)f2b(2.0f * s);
}

// Kernel 2: out[64][16384] = x@W^T + y2@B^T.  (exact R5 structure — best
// known at 92.3 us; nt reverted.)
__global__ void __launch_bounds__(256)
lora_gemm(const float* __restrict__ W,      // [16384][4096]
          const float* __restrict__ Bm,     // [16384][64]
          const ushort* __restrict__ xb,    // [64][4096] bf16
          const ushort* __restrict__ yb,    // [64][64] bf16
          float* __restrict__ out) {        // [64][16384]
    __shared__ ushort lds[2][16 * KT];      // 2 x 16 KB (bf16)

    const int tid  = threadIdx.x;
    const int w    = tid >> 6;              // wave 0..3 -> token group
    const int lane = tid & 63;
    const int c    = lane & 15;             // frag row/col index
    const int kg   = lane >> 4;             // k-group, offset kg*8
    const int j0   = blockIdx.x << 4;
    const int sx   = (c & 7) << 4;          // read-side swizzle

    const ushort* xrow = xb + (size_t)(w * 16 + c) * 4096 + kg * 8;

    f32x4 rg[4][2];                          // staged W: 4 rows x 2 chunks

    auto load_tile = [&](int t) {
        #pragma unroll
        for (int q = 0; q < 4; ++q) {
            const float* src = W + (size_t)(j0 + w * 4 + q) * 4096
                                 + (size_t)t * KT + lane * 4;
            rg[q][0] = *(const f32x4*)(src);
            rg[q][1] = *(const f32x4*)(src + 256);
        }
    };
    auto write_tile = [&](int buf) {
        #pragma unroll
        for (int q = 0; q < 4; ++q) {
            const int r = w * 4 + q;
            char* rowb = (char*)&lds[buf][0] + r * 1024;
            #pragma unroll
            for (int h = 0; h < 2; ++h) {
                s16x4 p;
                p[0] = f2b(rg[q][h][0]); p[1] = f2b(rg[q][h][1]);
                p[2] = f2b(rg[q][h][2]); p[3] = f2b(rg[q][h][3]);
                *(s16x4*)(rowb + ((h * 512 + lane * 8) ^ ((r & 7) << 4))) = p;
            }
        }
    };

    f32x4 acc = {0.f, 0.f, 0.f, 0.f};

    load_tile(0);
    write_tile(0);
    __syncthreads();

    for (int t = 0; t < NT; ++t) {
        const int cur = t & 1;
        if (t + 1 < NT) load_tile(t + 1);    // in flight under MFMA phase

        const char* lrow = (const char*)&lds[cur][0] + c * 1024;
        #pragma unroll
        for (int s = 0; s < 16; ++s) {
            bf16x8 bb = *(const bf16x8*)(lrow + ((s * 64 + kg * 16) ^ sx));
            bf16x8 aa = *(const bf16x8*)(xrow + (size_t)t * KT + s * 32);
            acc = __builtin_amdgcn_mfma_f32_16x16x32_bf16(aa, bb, acc, 0, 0, 0);
        }

        if (t + 1 < NT) {
            write_tile(cur ^ 1);             // other buffer; last read at t-1,
            __syncthreads();                 // protected by t-1's barrier
        }
    }

    // lora tail: 2 K-steps over r=64 with B matrix and y2
    {
        const float*  br = Bm + (size_t)(j0 + c) * 64 + kg * 8;
        const ushort* y0 = yb + (size_t)(w * 16 + c) * 64 + kg * 8;
        #pragma unroll
        for (int k = 0; k < 64; k += 32) {
            f32x4 w0 = *(const f32x4*)(br + k);
            f32x4 w1 = *(const f32x4*)(br + k + 4);
            bf16x8 bb;
            bb[0] = f2b(w0[0]); bb[1] = f2b(w0[1]);
            bb[2] = f2b(w0[2]); bb[3] = f2b(w0[3]);
            bb[4] = f2b(w1[0]); bb[5] = f2b(w1[1]);
            bb[6] = f2b(w1[2]); bb[7] = f2b(w1[3]);
            bf16x8 aa = *(const bf16x8*)(y0 + k);
            acc = __builtin_amdgcn_mfma_f32_16x16x32_bf16(aa, bb, acc, 0, 0, 0);
        }
    }

    // store: token row = w*16 + kg*4 + r, col = j0 + c
    float* op = out + j0 + c;
    #pragma unroll
    for (int r = 0; r < 4; ++r)
        op[(size_t)(w * 16 + kg * 4 + r) * 16384] = acc[r];
}

extern "C" void kernel_launch(void* const* d_in, const int* in_sizes, int n_in,
                              void* d_out, int out_size, void* d_ws, size_t ws_size,
                              hipStream_t stream) {
    const float* x  = (const float*)d_in[0];
    const float* W  = (const float*)d_in[1];
    const float* A  = (const float*)d_in[2];
    const float* Bm = (const float*)d_in[3];
    float* out = (float*)d_out;

    ushort* xb = (ushort*)d_ws;                          // 64*4096*2 = 524288 B
    ushort* yb = (ushort*)((char*)d_ws + 524288);        // 64*64*2   = 8192 B
    float*  sink = (float*)((char*)d_ws + (32 << 20));   // dead 2 MB region

    wread_bench<<<2048, 256, 0, stream>>>((const float4*)W, sink);
    prep_kernel<<<1024, 256, 0, stream>>>(x, A, xb, yb);
    lora_gemm<<<1024, 256, 0, stream>>>(W, Bm, xb, yb, out);
}

// Round 12
// 95.551 us; speedup vs baseline: 1.1796x; 1.1796x over previous
//
#include <hip/hip_runtime.h>
#include <hip/hip_bf16.h>

typedef __attribute__((ext_vector_type(8))) short bf16x8;
typedef __attribute__((ext_vector_type(4))) short s16x4;
typedef __attribute__((ext_vector_type(4))) float f32x4;

__device__ __forceinline__ short f2b(float f) {
    __hip_bfloat16 h = __float2bfloat16(f);   // RNE
    return __builtin_bit_cast(short, h);
}

#define KT 512      // K-tile in floats per phase (1 KB/row f32 halves)
#define NP 8        // 4096 / 512 phases

// Kernel 1: x f32 -> bf16, and y2 = 2*(x @ A^T) as bf16.
__global__ void prep_kernel(const float* __restrict__ x,
                            const float* __restrict__ A,
                            ushort* __restrict__ xb,     // [64][4096] bf16
                            ushort* __restrict__ yb) {   // [64][64] bf16
    const int tid = threadIdx.x, bid = blockIdx.x;

    const int gid = bid * 256 + tid;
    if (gid < 65536) {
        float4 v = ((const float4*)x)[gid];
        ushort4 s;
        s.x = (ushort)f2b(v.x); s.y = (ushort)f2b(v.y);
        s.z = (ushort)f2b(v.z); s.w = (ushort)f2b(v.w);
        ((ushort4*)xb)[gid] = s;
    }

    const int wave = tid >> 6, lane = tid & 63;
    const int idx = bid * 4 + wave;          // 0..4095
    const int t = idx >> 6, r = idx & 63;
    const float4* xr = (const float4*)(x + (size_t)t * 4096);
    const float4* ar = (const float4*)(A + (size_t)r * 4096);
    float s = 0.f;
    #pragma unroll
    for (int i = 0; i < 16; ++i) {
        float4 a = xr[i * 64 + lane];
        float4 b = ar[i * 64 + lane];
        s += a.x * b.x + a.y * b.y + a.z * b.z + a.w * b.w;
    }
    #pragma unroll
    for (int off = 32; off; off >>= 1) s += __shfl_xor(s, off, 64);
    if (lane == 0) yb[idx] = (ushort)f2b(2.0f * s);
}

// Kernel 2: out[64][16384] = x@W^T + y2@B^T.
// PRODUCER/CONSUMER WAVE SPECIALIZATION. 1024 blocks x 512 threads (8 waves),
// block owns W rows j0..j0+15.
//   waves 4..7 = STREAMERS: pure load pipes replicating the measured-6.6TB/s
//     wread pattern (8x contiguous-1KB lane-linear f32x4 loads per phase,
//     2 named reg banks, issue(p+1) BEFORE cvt(p) -> compiler emits counted
//     vmcnt(8); raw s_barrier + lgkmcnt(0) only, so the W vmcnt stream is
//     NEVER drained and never mixed with consume-side waits).
//   waves 0..3 = CONSUMERS: one 16-token MFMA group each; x-loads (L2) live
//     in their own per-wave vmcnt; __syncthreads (its vmcnt drain only hits
//     consumer's own fast loads).
__global__ void __launch_bounds__(512, 4)
lora_gemm(const float* __restrict__ W,      // [16384][4096]
          const float* __restrict__ Bm,     // [16384][64]
          const ushort* __restrict__ xb,    // [64][4096] bf16
          const ushort* __restrict__ yb,    // [64][64] bf16
          float* __restrict__ out) {        // [64][16384]
    __shared__ ushort lds[2][16 * KT];      // 2 x 16 KB (bf16)

    const int tid  = threadIdx.x;
    const int w    = tid >> 6;              // wave id 0..7
    const int lane = tid & 63;
    const int j0   = blockIdx.x << 4;

    if (w >= 4) {
        // ---------------- STREAMER (waves 4..7) ----------------
        const int sw = w - 4;               // 0..3, handles rows sw*4..sw*4+3
        f32x4 bkA[8], bkB[8];               // named banks (static idx, rule 20)

        // load i: row sw*4+(i>>1), half (i&1): 1 KB contiguous, lane-linear
        #define ISSUE(bk, p)                                                \
            { _Pragma("unroll")                                             \
              for (int i = 0; i < 8; ++i) {                                 \
                  const float* src = W                                      \
                      + (size_t)(j0 + sw * 4 + (i >> 1)) * 4096             \
                      + (size_t)(p) * KT + (i & 1) * 256 + lane * 4;        \
                  bk[i] = *(const f32x4*)src;                               \
              } }

        // cvt f32->bf16, XOR-swizzled ds_write (matches consumer read side)
        #define CVTW(bk, buf)                                               \
            { _Pragma("unroll")                                             \
              for (int i = 0; i < 8; ++i) {                                 \
                  const int rq = sw * 4 + (i >> 1);                         \
                  s16x4 p_;                                                 \
                  p_[0] = f2b(bk[i][0]); p_[1] = f2b(bk[i][1]);             \
                  p_[2] = f2b(bk[i][2]); p_[3] = f2b(bk[i][3]);             \
                  *(s16x4*)((char*)&lds[buf][0] + rq * 1024                 \
                      + (((i & 1) * 512 + lane * 8) ^ ((rq & 7) << 4)))     \
                      = p_;                                                 \
              } }

        #define SBAR()                                                      \
            asm volatile("s_waitcnt lgkmcnt(0)" ::: "memory");              \
            __builtin_amdgcn_s_barrier();

        // prologue: issue ph0+ph1, cvt ph0 (auto vmcnt(8): ph1 stays in flight)
        ISSUE(bkA, 0);
        ISSUE(bkB, 1);
        CVTW(bkA, 0);
        SBAR();                              // buf0 ready

        #pragma unroll
        for (int p = 0; p < NP; p += 2) {
            if (p + 2 < NP) ISSUE(bkA, p + 2);
            if (p + 1 < NP) CVTW(bkB, 1);    // auto vmcnt(8), bkA in flight
            SBAR();                          // buf1 ready
            if (p + 3 < NP) ISSUE(bkB, p + 3);
            if (p + 2 < NP) CVTW(bkA, 0);
            SBAR();                          // buf0 ready
        }
        #undef ISSUE
        #undef CVTW
        #undef SBAR
        return;
    }

    // ---------------- CONSUMER (waves 0..3) ----------------
    const int cw = w;                        // token group cw*16..cw*16+15
    const int c  = lane & 15;                // token row / output col index
    const int kg = lane >> 4;                // k-group, offset kg*8
    const int sx = (c & 7) << 4;             // read-side swizzle

    const ushort* xrow = xb + (size_t)(cw * 16 + c) * 4096 + kg * 8;
    f32x4 acc = {0.f, 0.f, 0.f, 0.f};

    __syncthreads();                         // matches streamer prologue SBAR

    for (int p = 0; p < NP; ++p) {
        const char* lrow = (const char*)&lds[p & 1][0] + c * 1024;
        #pragma unroll
        for (int s = 0; s < 16; ++s) {
            bf16x8 bb = *(const bf16x8*)(lrow + ((s * 64 + kg * 16) ^ sx));
            bf16x8 aa = *(const bf16x8*)(xrow + (size_t)p * KT + s * 32);
            acc = __builtin_amdgcn_mfma_f32_16x16x32_bf16(aa, bb, acc, 0, 0, 0);
        }
        __syncthreads();                     // matches streamer per-phase SBAR
    }

    // lora tail: 2 K-steps over r=64 with B matrix and y2
    {
        const float*  br = Bm + (size_t)(j0 + c) * 64 + kg * 8;
        const ushort* y0 = yb + (size_t)(cw * 16 + c) * 64 + kg * 8;
        #pragma unroll
        for (int k = 0; k < 64; k += 32) {
            f32x4 w0 = *(const f32x4*)(br + k);
            f32x4 w1 = *(const f32x4*)(br + k + 4);
            bf16x8 bb;
            bb[0] = f2b(w0[0]); bb[1] = f2b(w0[1]);
            bb[2] = f2b(w0[2]); bb[3] = f2b(w0[3]);
            bb[4] = f2b(w1[0]); bb[5] = f2b(w1[1]);
            bb[6] = f2b(w1[2]); bb[7] = f2b(w1[3]);
            bf16x8 aa = *(const bf16x8*)(y0 + k);
            acc = __builtin_amdgcn_mfma_f32_16x16x32_bf16(aa, bb, acc, 0, 0, 0);
        }
    }

    // store: token row = cw*16 + kg*4 + r, col = j0 + c
    float* op = out + j0 + c;
    #pragma unroll
    for (int r = 0; r < 4; ++r)
        op[(size_t)(cw * 16 + kg * 4 + r) * 16384] = acc[r];
}

extern "C" void kernel_launch(void* const* d_in, const int* in_sizes, int n_in,
                              void* d_out, int out_size, void* d_ws, size_t ws_size,
                              hipStream_t stream) {
    const float* x  = (const float*)d_in[0];
    const float* W  = (const float*)d_in[1];
    const float* A  = (const float*)d_in[2];
    const float* Bm = (const float*)d_in[3];
    float* out = (float*)d_out;

    ushort* xb = (ushort*)d_ws;                          // 64*4096*2 = 524288 B
    ushort* yb = (ushort*)((char*)d_ws + 524288);        // 64*64*2   = 8192 B

    prep_kernel<<<1024, 256, 0, stream>>>(x, A, xb, yb);
    lora_gemm<<<1024, 512, 0, stream>>>(W, Bm, xb, yb, out);
}

// Round 13
// 64.989 us; speedup vs baseline: 1.7343x; 1.4703x over previous
//
#include <hip/hip_runtime.h>
#include <hip/hip_bf16.h>

typedef __attribute__((ext_vector_type(8))) short bf16x8;
typedef __attribute__((ext_vector_type(4))) short s16x4;
typedef __attribute__((ext_vector_type(4))) float f32x4;

__device__ __forceinline__ short f2b(float f) {
    __hip_bfloat16 h = __float2bfloat16(f);   // RNE
    return __builtin_bit_cast(short, h);
}

#define NPH 16
#define KC  256     // floats per row per phase (1 KB f32 / 512 B bf16)

// Kernel 1: x f32 -> bf16, and y2 = 2*(x @ A^T) as bf16.
__global__ void prep_kernel(const float* __restrict__ x,
                            const float* __restrict__ A,
                            ushort* __restrict__ xb,     // [64][4096] bf16
                            ushort* __restrict__ yb) {   // [64][64] bf16
    const int tid = threadIdx.x, bid = blockIdx.x;

    const int gid = bid * 256 + tid;
    if (gid < 65536) {
        float4 v = ((const float4*)x)[gid];
        ushort4 s;
        s.x = (ushort)f2b(v.x); s.y = (ushort)f2b(v.y);
        s.z = (ushort)f2b(v.z); s.w = (ushort)f2b(v.w);
        ((ushort4*)xb)[gid] = s;
    }

    const int wave = tid >> 6, lane = tid & 63;
    const int idx = bid * 4 + wave;          // 0..4095
    const int t = idx >> 6, r = idx & 63;
    const float4* xr = (const float4*)(x + (size_t)t * 4096);
    const float4* ar = (const float4*)(A + (size_t)r * 4096);
    float s = 0.f;
    #pragma unroll
    for (int i = 0; i < 16; ++i) {
        float4 a = xr[i * 64 + lane];
        float4 b = ar[i * 64 + lane];
        s += a.x * b.x + a.y * b.y + a.z * b.z + a.w * b.w;
    }
    #pragma unroll
    for (int off = 32; off; off >>= 1) s += __shfl_xor(s, off, 64);
    if (lane == 0) yb[idx] = (ushort)f2b(2.0f * s);
}

// Kernel 2: out[64][16384] = x@W^T + y2@B^T.
// 256 blocks x 512 threads (1 block/CU). Block owns 64 W-rows (contiguous
// 1 MB region) -> xb is read ONCE per block: chip-wide x-traffic drops
// 512 MB -> 128 MB (the R1..R12 constant: W + x delivered ~9.5 TB/s total;
// x was starving W. Freed budget goes to W.)
//   waves 4..7 = streamers: 16 x 1 KB lane-linear W loads per phase,
//     grouped counted-vmcnt cvt -> swizzled ds_write; raw s_barrier +
//     lgkmcnt(0) only (vmcnt never force-drained).
//   waves 0..3 = consumers: 16 tokens x 64 cols, 4 MFMA chains; LDS b-frag
//     reads are uniform 8-lanes-per-16B-slot = conflict-free.
// Barriers: streamer 16 (one per fill), consumer 16 (B0 + after phases
// 0..14); streamers exit after fill 15, consumers run phase 15 barrier-free.
__global__ void __launch_bounds__(512)
lora_gemm(const float* __restrict__ W,      // [16384][4096]
          const float* __restrict__ Bm,     // [16384][64]
          const ushort* __restrict__ xb,    // [64][4096] bf16
          const ushort* __restrict__ yb,    // [64][64] bf16
          float* __restrict__ out) {        // [64][16384]
    __shared__ ushort buf[2][64 * KC];      // 2 x 32 KB

    const int tid  = threadIdx.x;
    const int w    = tid >> 6;              // wave 0..7
    const int lane = tid & 63;
    const int j0   = blockIdx.x << 6;       // 64 W-rows / out-cols per block

    if (w >= 4) {
        // ---------------- STREAMER (waves 4..7): rows s*16 .. s*16+15 ----
        const int s = w - 4;
        f32x4 st[16];
        for (int p = 0; p < NPH; ++p) {
            char* dst = (char*)&buf[p & 1][0];
            #pragma unroll
            for (int i = 0; i < 16; ++i) {
                const float* src = W + (size_t)(j0 + s * 16 + i) * 4096
                                     + p * KC + lane * 4;
                st[i] = *(const f32x4*)src;
            }
            #pragma unroll
            for (int i = 0; i < 16; ++i) {   // counted vmcnt: st[i] in order
                const int q = s * 16 + i;
                s16x4 v;
                v[0] = f2b(st[i][0]); v[1] = f2b(st[i][1]);
                v[2] = f2b(st[i][2]); v[3] = f2b(st[i][3]);
                *(s16x4*)(dst + q * 512 + ((lane * 8) ^ ((q & 7) << 4))) = v;
            }
            asm volatile("s_waitcnt lgkmcnt(0)" ::: "memory");
            __builtin_amdgcn_s_barrier();    // fill-p visible
        }
        return;
    }

    // ---------------- CONSUMER (waves 0..3): tokens w*16..w*16+15 --------
    const int c  = lane & 15;               // token row / D-col index
    const int kg = lane >> 4;               // k-group, offset kg*8
    const ushort* xrow = xb + (size_t)(w * 16 + c) * 4096 + kg * 8;

    f32x4 acc[4];
    #pragma unroll
    for (int n = 0; n < 4; ++n) acc[n] = f32x4{0.f, 0.f, 0.f, 0.f};

    __builtin_amdgcn_s_barrier();           // B0: panel 0 ready

    for (int p = 0; p < NPH; ++p) {
        const char* lb = (const char*)&buf[p & 1][0];
        #pragma unroll
        for (int sl = 0; sl < 8; ++sl) {
            bf16x8 aa = *(const bf16x8*)(xrow + p * KC + sl * 32);
            #pragma unroll
            for (int n = 0; n < 4; ++n) {
                const int q = n * 16 + c;    // W-row within block = D col
                bf16x8 bb = *(const bf16x8*)(lb + q * 512
                    + ((sl * 64 + kg * 16) ^ ((q & 7) << 4)));
                acc[n] = __builtin_amdgcn_mfma_f32_16x16x32_bf16(
                    aa, bb, acc[n], 0, 0, 0);
            }
        }
        if (p + 1 < NPH) {
            asm volatile("s_waitcnt lgkmcnt(0)" ::: "memory");
            __builtin_amdgcn_s_barrier();    // B(p+1)
        }
    }

    // lora tail: 2 K-steps over r=64 per col-subtile
    {
        const ushort* y0 = yb + (size_t)(w * 16 + c) * 64 + kg * 8;
        #pragma unroll
        for (int n = 0; n < 4; ++n) {
            const float* br = Bm + (size_t)(j0 + n * 16 + c) * 64 + kg * 8;
            #pragma unroll
            for (int k = 0; k < 64; k += 32) {
                f32x4 w0 = *(const f32x4*)(br + k);
                f32x4 w1 = *(const f32x4*)(br + k + 4);
                bf16x8 bb;
                bb[0] = f2b(w0[0]); bb[1] = f2b(w0[1]);
                bb[2] = f2b(w0[2]); bb[3] = f2b(w0[3]);
                bb[4] = f2b(w1[0]); bb[5] = f2b(w1[1]);
                bb[6] = f2b(w1[2]); bb[7] = f2b(w1[3]);
                bf16x8 aa = *(const bf16x8*)(y0 + k);
                acc[n] = __builtin_amdgcn_mfma_f32_16x16x32_bf16(
                    aa, bb, acc[n], 0, 0, 0);
            }
        }
    }

    // store: token row = w*16 + kg*4 + r, col = j0 + n*16 + c
    #pragma unroll
    for (int n = 0; n < 4; ++n) {
        float* op = out + j0 + n * 16 + c;
        #pragma unroll
        for (int r = 0; r < 4; ++r)
            op[(size_t)(w * 16 + kg * 4 + r) * 16384] = acc[n][r];
    }
}

extern "C" void kernel_launch(void* const* d_in, const int* in_sizes, int n_in,
                              void* d_out, int out_size, void* d_ws, size_t ws_size,
                              hipStream_t stream) {
    const float* x  = (const float*)d_in[0];
    const float* W  = (const float*)d_in[1];
    const float* A  = (const float*)d_in[2];
    const float* Bm = (const float*)d_in[3];
    float* out = (float*)d_out;

    ushort* xb = (ushort*)d_ws;                          // 64*4096*2 = 524288 B
    ushort* yb = (ushort*)((char*)d_ws + 524288);        // 64*64*2   = 8192 B

    prep_kernel<<<1024, 256, 0, stream>>>(x, A, xb, yb);
    lora_gemm<<<256, 512, 0, stream>>>(W, Bm, xb, yb, out);
}